// Round 1
// baseline (2834.493 us; speedup 1.0000x reference)
//
#include <hip/hip_runtime.h>

#define N_NODES 100000
#define N_EDGES 1600000
#define IN_F 256
#define OUT_F 128

// ---------------------------------------------------------------------------
// GEMM: support[N_NODES][128] = x[N_NODES][256] @ w[256][128]
// Tile: BM=128 rows, BN=128 (all cols), BK=32. 256 threads, 8x8 per thread.
// xs_t stored transposed [k][row] with row-stride 132 (16B-aligned b128 reads,
// <=2-way bank aliasing on reads). ws stored linear [k][col].
// ---------------------------------------------------------------------------
__global__ __launch_bounds__(256) void gemm_kernel(const float* __restrict__ x,
                                                   const float* __restrict__ w,
                                                   float* __restrict__ support) {
    __shared__ float xs[32][132];  // [k][row], padded stride 132
    __shared__ float ws[32][128];  // [k][col]

    const int tid = threadIdx.x;
    const int tx = tid & 15;   // col group: cols {tx*4..+3, 64+tx*4..+3}
    const int ty = tid >> 4;   // row group: rows {ty*4..+3, 64+ty*4..+3}
    const int row0 = blockIdx.x * 128;

    float acc[8][8];
#pragma unroll
    for (int i = 0; i < 8; ++i)
#pragma unroll
        for (int j = 0; j < 8; ++j) acc[i][j] = 0.0f;

    const int lrow = tid >> 3;  // 0..31 (row within 32-row group)
    const int lkq  = tid & 7;   // 0..7  (k-quad within BK=32)

    for (int kt = 0; kt < 8; ++kt) {
        __syncthreads();  // previous tile fully consumed before overwrite
        // stage x tile (transposed): 128 rows x 32 k
#pragma unroll
        for (int i = 0; i < 4; ++i) {
            int r = lrow + 32 * i;
            int grow = row0 + r;
            float4 v = make_float4(0.f, 0.f, 0.f, 0.f);
            if (grow < N_NODES)
                v = *reinterpret_cast<const float4*>(&x[grow * IN_F + kt * 32 + lkq * 4]);
            xs[lkq * 4 + 0][r] = v.x;
            xs[lkq * 4 + 1][r] = v.y;
            xs[lkq * 4 + 2][r] = v.z;
            xs[lkq * 4 + 3][r] = v.w;
        }
        // stage w tile: contiguous 32*128 floats
#pragma unroll
        for (int i = 0; i < 4; ++i) {
            int idx = tid + 256 * i;  // float4 index 0..1023
            float4 v = *reinterpret_cast<const float4*>(&w[kt * 32 * OUT_F + idx * 4]);
            reinterpret_cast<float4*>(&ws[0][0])[idx] = v;
        }
        __syncthreads();

#pragma unroll
        for (int k = 0; k < 32; ++k) {
            float4 a0 = *reinterpret_cast<const float4*>(&xs[k][ty * 4]);
            float4 a1 = *reinterpret_cast<const float4*>(&xs[k][64 + ty * 4]);
            float4 b0 = *reinterpret_cast<const float4*>(&ws[k][tx * 4]);
            float4 b1 = *reinterpret_cast<const float4*>(&ws[k][64 + tx * 4]);
            float a[8] = {a0.x, a0.y, a0.z, a0.w, a1.x, a1.y, a1.z, a1.w};
            float b[8] = {b0.x, b0.y, b0.z, b0.w, b1.x, b1.y, b1.z, b1.w};
#pragma unroll
            for (int i = 0; i < 8; ++i)
#pragma unroll
                for (int j = 0; j < 8; ++j) acc[i][j] += a[i] * b[j];
        }
    }

    // epilogue: write support
#pragma unroll
    for (int i = 0; i < 8; ++i) {
        int r = row0 + (i >> 2) * 64 + ty * 4 + (i & 3);
        if (r < N_NODES) {
            float4 c0 = {acc[i][0], acc[i][1], acc[i][2], acc[i][3]};
            float4 c1 = {acc[i][4], acc[i][5], acc[i][6], acc[i][7]};
            *reinterpret_cast<float4*>(&support[r * OUT_F + tx * 4]) = c0;
            *reinterpret_cast<float4*>(&support[r * OUT_F + 64 + tx * 4]) = c1;
        }
    }
}

// ---------------------------------------------------------------------------
// out[i][f] = bias[f]  (poisoned d_out -> must fully initialize)
// ---------------------------------------------------------------------------
__global__ __launch_bounds__(256) void init_out_kernel(float* __restrict__ out,
                                                       const float* __restrict__ bias) {
    int gid = blockIdx.x * 256 + threadIdx.x;  // float4 index
    const int total4 = N_NODES * OUT_F / 4;    // 3.2M
    if (gid < total4) {
        int f4 = gid & (OUT_F / 4 - 1);  // 0..31
        float4 b = reinterpret_cast<const float4*>(bias)[f4];
        reinterpret_cast<float4*>(out)[gid] = b;
    }
}

// ---------------------------------------------------------------------------
// scatter: for each edge e: out[row[e]][:] += val[e] * support[col[e]][:]
// 32 threads per edge, float4 per thread, f32 atomics.
// ---------------------------------------------------------------------------
__global__ __launch_bounds__(256) void scatter_kernel(const float* __restrict__ support,
                                                      const float* __restrict__ val,
                                                      const int* __restrict__ rowi,
                                                      const int* __restrict__ coli,
                                                      float* out) {
    int gid = blockIdx.x * 256 + threadIdx.x;
    int e = gid >> 5;
    if (e >= N_EDGES) return;
    int f = (gid & 31) * 4;
    int src = coli[e];
    int dst = rowi[e];
    float v = val[e];
    float4 s = *reinterpret_cast<const float4*>(&support[src * OUT_F + f]);
    float* o = &out[dst * OUT_F + f];
    atomicAdd(o + 0, s.x * v);
    atomicAdd(o + 1, s.y * v);
    atomicAdd(o + 2, s.z * v);
    atomicAdd(o + 3, s.w * v);
}

extern "C" void kernel_launch(void* const* d_in, const int* in_sizes, int n_in,
                              void* d_out, int out_size, void* d_ws, size_t ws_size,
                              hipStream_t stream) {
    const float* x      = (const float*)d_in[0];
    const float* weight = (const float*)d_in[1];
    const float* bias   = (const float*)d_in[2];
    const float* adj_val = (const float*)d_in[3];
    const int*   adj_row = (const int*)d_in[4];
    const int*   adj_col = (const int*)d_in[5];
    float* out = (float*)d_out;
    float* support = (float*)d_ws;  // 100000*128*4 = 51.2 MB

    // 1) support = x @ weight
    int gemm_blocks = (N_NODES + 127) / 128;  // 782
    gemm_kernel<<<gemm_blocks, 256, 0, stream>>>(x, weight, support);

    // 2) out = bias (broadcast)
    int init_blocks = (N_NODES * OUT_F / 4 + 255) / 256;  // 12500
    init_out_kernel<<<init_blocks, 256, 0, stream>>>(out, bias);

    // 3) scatter-accumulate edges
    long long scatter_threads = (long long)N_EDGES * 32;
    int scatter_blocks = (int)((scatter_threads + 255) / 256);  // 200000
    scatter_kernel<<<scatter_blocks, 256, 0, stream>>>(support, adj_val, adj_row, adj_col, out);
}

// Round 2
// 460.787 us; speedup vs baseline: 6.1514x; 6.1514x over previous
//
#include <hip/hip_runtime.h>

#define N_NODES 100000
#define N_EDGES 1600000
#define IN_F 256
#define OUT_F 128

// ---------------------------------------------------------------------------
// GEMM: support[N_NODES][128] = x[N_NODES][256] @ w[256][128]
// (unchanged from round 0 — optimize after the scatter is fixed)
// ---------------------------------------------------------------------------
__global__ __launch_bounds__(256) void gemm_kernel(const float* __restrict__ x,
                                                   const float* __restrict__ w,
                                                   float* __restrict__ support) {
    __shared__ float xs[32][132];  // [k][row], padded stride 132
    __shared__ float ws[32][128];  // [k][col]

    const int tid = threadIdx.x;
    const int tx = tid & 15;
    const int ty = tid >> 4;
    const int row0 = blockIdx.x * 128;

    float acc[8][8];
#pragma unroll
    for (int i = 0; i < 8; ++i)
#pragma unroll
        for (int j = 0; j < 8; ++j) acc[i][j] = 0.0f;

    const int lrow = tid >> 3;
    const int lkq  = tid & 7;

    for (int kt = 0; kt < 8; ++kt) {
        __syncthreads();
#pragma unroll
        for (int i = 0; i < 4; ++i) {
            int r = lrow + 32 * i;
            int grow = row0 + r;
            float4 v = make_float4(0.f, 0.f, 0.f, 0.f);
            if (grow < N_NODES)
                v = *reinterpret_cast<const float4*>(&x[grow * IN_F + kt * 32 + lkq * 4]);
            xs[lkq * 4 + 0][r] = v.x;
            xs[lkq * 4 + 1][r] = v.y;
            xs[lkq * 4 + 2][r] = v.z;
            xs[lkq * 4 + 3][r] = v.w;
        }
#pragma unroll
        for (int i = 0; i < 4; ++i) {
            int idx = tid + 256 * i;
            float4 v = *reinterpret_cast<const float4*>(&w[kt * 32 * OUT_F + idx * 4]);
            reinterpret_cast<float4*>(&ws[0][0])[idx] = v;
        }
        __syncthreads();

#pragma unroll
        for (int k = 0; k < 32; ++k) {
            float4 a0 = *reinterpret_cast<const float4*>(&xs[k][ty * 4]);
            float4 a1 = *reinterpret_cast<const float4*>(&xs[k][64 + ty * 4]);
            float4 b0 = *reinterpret_cast<const float4*>(&ws[k][tx * 4]);
            float4 b1 = *reinterpret_cast<const float4*>(&ws[k][64 + tx * 4]);
            float a[8] = {a0.x, a0.y, a0.z, a0.w, a1.x, a1.y, a1.z, a1.w};
            float b[8] = {b0.x, b0.y, b0.z, b0.w, b1.x, b1.y, b1.z, b1.w};
#pragma unroll
            for (int i = 0; i < 8; ++i)
#pragma unroll
                for (int j = 0; j < 8; ++j) acc[i][j] += a[i] * b[j];
        }
    }

#pragma unroll
    for (int i = 0; i < 8; ++i) {
        int r = row0 + (i >> 2) * 64 + ty * 4 + (i & 3);
        if (r < N_NODES) {
            float4 c0 = {acc[i][0], acc[i][1], acc[i][2], acc[i][3]};
            float4 c1 = {acc[i][4], acc[i][5], acc[i][6], acc[i][7]};
            *reinterpret_cast<float4*>(&support[r * OUT_F + tx * 4]) = c0;
            *reinterpret_cast<float4*>(&support[r * OUT_F + 64 + tx * 4]) = c1;
        }
    }
}

// ---------------------------------------------------------------------------
// CSR build: counting sort of edges by destination node.
// ---------------------------------------------------------------------------
__global__ __launch_bounds__(256) void zero_kernel(int* __restrict__ p, int n) {
    int i = blockIdx.x * 256 + threadIdx.x;
    if (i < n) p[i] = 0;
}

__global__ __launch_bounds__(256) void hist_kernel(const int* __restrict__ rowi,
                                                   int* __restrict__ counts) {
    int e = blockIdx.x * 256 + threadIdx.x;
    if (e < N_EDGES) atomicAdd(&counts[rowi[e]], 1);
}

// scan1: per-block (1024 elems) exclusive scan in place + block sums.
__global__ __launch_bounds__(256) void scan1_kernel(int* __restrict__ data,
                                                    int* __restrict__ blocksums,
                                                    int n) {
    __shared__ int sdata[256];
    const int tid = threadIdx.x;
    const int base = blockIdx.x * 1024 + tid * 4;
    int v0 = (base + 0 < n) ? data[base + 0] : 0;
    int v1 = (base + 1 < n) ? data[base + 1] : 0;
    int v2 = (base + 2 < n) ? data[base + 2] : 0;
    int v3 = (base + 3 < n) ? data[base + 3] : 0;
    int s1 = v0 + v1, s2 = s1 + v2, s3 = s2 + v3;
    sdata[tid] = s3;
    __syncthreads();
#pragma unroll
    for (int off = 1; off < 256; off <<= 1) {
        int t = (tid >= off) ? sdata[tid - off] : 0;
        __syncthreads();
        sdata[tid] += t;
        __syncthreads();
    }
    int excl = (tid == 0) ? 0 : sdata[tid - 1];
    if (base + 0 < n) data[base + 0] = excl;
    if (base + 1 < n) data[base + 1] = excl + v0;
    if (base + 2 < n) data[base + 2] = excl + s1;
    if (base + 3 < n) data[base + 3] = excl + s2;
    if (tid == 255) blocksums[blockIdx.x] = sdata[255];
}

// scan2: single block exclusive scan of block sums (nblk <= 128).
__global__ __launch_bounds__(128) void scan2_kernel(int* __restrict__ blocksums, int nblk) {
    __shared__ int sdata[128];
    const int tid = threadIdx.x;
    sdata[tid] = (tid < nblk) ? blocksums[tid] : 0;
    __syncthreads();
#pragma unroll
    for (int off = 1; off < 128; off <<= 1) {
        int t = (tid >= off) ? sdata[tid - off] : 0;
        __syncthreads();
        sdata[tid] += t;
        __syncthreads();
    }
    if (tid < nblk) blocksums[tid] = (tid == 0) ? 0 : sdata[tid - 1];
}

// scan3: add block bases.
__global__ __launch_bounds__(256) void scan3_kernel(int* __restrict__ data,
                                                    const int* __restrict__ blocksums,
                                                    int n) {
    int i = blockIdx.x * 1024 + threadIdx.x * 4;
    int b = blocksums[blockIdx.x];
    if (i + 0 < n) data[i + 0] += b;
    if (i + 1 < n) data[i + 1] += b;
    if (i + 2 < n) data[i + 2] += b;
    if (i + 3 < n) data[i + 3] += b;
}

// scatter edges into dst-grouped order. offsets[] holds start positions;
// after this kernel, offsets[i] == end position of node i (start of i+1).
__global__ __launch_bounds__(256) void sortscat_kernel(const int* __restrict__ rowi,
                                                       const int* __restrict__ coli,
                                                       const float* __restrict__ val,
                                                       int* __restrict__ offsets,
                                                       uint2* __restrict__ pairs) {
    int e = blockIdx.x * 256 + threadIdx.x;
    if (e < N_EDGES) {
        int dst = rowi[e];
        int pos = atomicAdd(&offsets[dst], 1);
        pairs[pos] = make_uint2((unsigned)coli[e], __float_as_uint(val[e]));
    }
}

// ---------------------------------------------------------------------------
// accumulate: one wave64 per node. 32 lanes (float4 each) cover 128 feats;
// the two wave halves process alternating edges, combined via shfl_xor(32).
// Writes out = acc + bias. No float atomics anywhere.
// ---------------------------------------------------------------------------
__global__ __launch_bounds__(256) void accum_kernel(const float* __restrict__ support,
                                                    const uint2* __restrict__ pairs,
                                                    const int* __restrict__ offsets,
                                                    const float* __restrict__ bias,
                                                    float* __restrict__ out) {
    const int node = blockIdx.x * 4 + (threadIdx.x >> 6);
    const int lane = threadIdx.x & 63;
    const int half = lane >> 5;
    const int f4 = lane & 31;
    if (node >= N_NODES) return;

    const int start = (node == 0) ? 0 : offsets[node - 1];
    const int end = offsets[node];

    float4 acc = make_float4(0.f, 0.f, 0.f, 0.f);
    for (int p = start + half; p < end; p += 2) {
        uint2 pr = pairs[p];
        float v = __uint_as_float(pr.y);
        float4 s = *reinterpret_cast<const float4*>(&support[(size_t)pr.x * OUT_F + f4 * 4]);
        acc.x += s.x * v;
        acc.y += s.y * v;
        acc.z += s.z * v;
        acc.w += s.w * v;
    }
    // combine the two halves
    acc.x += __shfl_xor(acc.x, 32);
    acc.y += __shfl_xor(acc.y, 32);
    acc.z += __shfl_xor(acc.z, 32);
    acc.w += __shfl_xor(acc.w, 32);

    if (half == 0) {
        float4 b = *reinterpret_cast<const float4*>(&bias[f4 * 4]);
        float4 o = make_float4(acc.x + b.x, acc.y + b.y, acc.z + b.z, acc.w + b.w);
        *reinterpret_cast<float4*>(&out[(size_t)node * OUT_F + f4 * 4]) = o;
    }
}

extern "C" void kernel_launch(void* const* d_in, const int* in_sizes, int n_in,
                              void* d_out, int out_size, void* d_ws, size_t ws_size,
                              hipStream_t stream) {
    const float* x       = (const float*)d_in[0];
    const float* weight  = (const float*)d_in[1];
    const float* bias    = (const float*)d_in[2];
    const float* adj_val = (const float*)d_in[3];
    const int*   adj_row = (const int*)d_in[4];
    const int*   adj_col = (const int*)d_in[5];
    float* out = (float*)d_out;

    // workspace layout (all 8B-aligned):
    //   support   : 12,800,000 floats (51.2 MB)
    //   offsets   : 100,000 ints  (counts -> exclusive scan -> post-scatter ends)
    //   blocksums : 128 ints  (+ pad to keep pairs 8B-aligned)
    //   pairs     : 1,600,000 uint2 (12.8 MB)
    float* support = (float*)d_ws;
    int* offsets = (int*)(support + (size_t)N_NODES * OUT_F);
    int* blocksums = offsets + 100000;
    uint2* pairs = (uint2*)(blocksums + 132);  // 100000+132 ints = even -> 8B aligned

    const int NSCAN_BLOCKS = (N_NODES + 1023) / 1024;  // 98

    // 1) support = x @ weight
    gemm_kernel<<<(N_NODES + 127) / 128, 256, 0, stream>>>(x, weight, support);

    // 2) CSR build
    zero_kernel<<<(N_NODES + 255) / 256, 256, 0, stream>>>(offsets, N_NODES);
    hist_kernel<<<(N_EDGES + 255) / 256, 256, 0, stream>>>(adj_row, offsets);
    scan1_kernel<<<NSCAN_BLOCKS, 256, 0, stream>>>(offsets, blocksums, N_NODES);
    scan2_kernel<<<1, 128, 0, stream>>>(blocksums, NSCAN_BLOCKS);
    scan3_kernel<<<NSCAN_BLOCKS, 256, 0, stream>>>(offsets, blocksums, N_NODES);
    sortscat_kernel<<<(N_EDGES + 255) / 256, 256, 0, stream>>>(adj_row, adj_col, adj_val,
                                                               offsets, pairs);

    // 3) accumulate per destination node (no float atomics)
    accum_kernel<<<(N_NODES + 3) / 4, 256, 0, stream>>>(support, pairs, offsets, bias, out);
}

// Round 3
// 319.695 us; speedup vs baseline: 8.8662x; 1.4413x over previous
//
#include <hip/hip_runtime.h>

#define N_NODES 100000
#define N_EDGES 1600000
#define IN_F 256
#define OUT_F 128
#define LDK 40  // padded k-stride (bf16 elems) for LDS tiles

typedef __attribute__((ext_vector_type(8))) short bf16x8;
typedef __attribute__((ext_vector_type(4))) float f32x4;

__device__ __forceinline__ unsigned short f2bf(float f) {
    unsigned u = __float_as_uint(f);
    unsigned r = u + 0x7fffu + ((u >> 16) & 1u);  // RNE
    return (unsigned short)(r >> 16);
}
__device__ __forceinline__ float bf2f(unsigned short u) {
    return __uint_as_float(((unsigned)u) << 16);
}

// ---------------------------------------------------------------------------
// wt[col][k] (bf16) = w[k][col]  — one-time transpose+convert, 32K elems.
// ---------------------------------------------------------------------------
__global__ __launch_bounds__(256) void wtrans_kernel(const float* __restrict__ w,
                                                     unsigned short* __restrict__ wt) {
    int c = blockIdx.x;       // 0..127
    int k = threadIdx.x;      // 0..255
    wt[c * IN_F + k] = f2bf(w[k * OUT_F + c]);
}

// ---------------------------------------------------------------------------
// GEMM: support_bf16[N][128] = bf16(x[N][256]) @ bf16(w[256][128])
// 128x128 tile, 4 waves (2x2), 4x4 16x16x32 frags per wave, BK=32, 8 k-steps.
// ---------------------------------------------------------------------------
__global__ __launch_bounds__(256) void gemm_mfma_kernel(const float* __restrict__ x,
                                                        const unsigned short* __restrict__ wt,
                                                        unsigned short* __restrict__ support) {
    __shared__ unsigned short xs[128 * LDK];  // [row][k] bf16, stride 40
    __shared__ unsigned short ws[128 * LDK];  // [col][k] bf16, stride 40

    const int tid = threadIdx.x;
    const int lane = tid & 63;
    const int wv = tid >> 6;
    const int wr = (wv >> 1) * 64;  // wave row offset in tile
    const int wc = (wv & 1) * 64;   // wave col offset in tile
    const int row0 = blockIdx.x * 128;
    const int l15 = lane & 15;
    const int kg = (lane >> 4) * 8;  // k-group offset within BK

    f32x4 acc[4][4];
#pragma unroll
    for (int m = 0; m < 4; ++m)
#pragma unroll
        for (int n = 0; n < 4; ++n) acc[m][n] = (f32x4){0.f, 0.f, 0.f, 0.f};

    for (int kt = 0; kt < 8; ++kt) {
        __syncthreads();
        // stage x tile: 128 rows x 32 k, f32 -> bf16 (clamp OOB rows; their
        // acc is never stored)
#pragma unroll
        for (int i = 0; i < 4; ++i) {
            int idx = tid + 256 * i;  // 0..1023 float4-chunks
            int r = idx >> 3, q = idx & 7;
            int grow = row0 + r;
            if (grow > N_NODES - 1) grow = N_NODES - 1;
            float4 v = *reinterpret_cast<const float4*>(&x[(size_t)grow * IN_F + kt * 32 + q * 4]);
            ushort4 b;
            b.x = f2bf(v.x); b.y = f2bf(v.y); b.z = f2bf(v.z); b.w = f2bf(v.w);
            *reinterpret_cast<ushort4*>(&xs[r * LDK + q * 4]) = b;
        }
        // stage wT tile: 128 cols x 32 k bf16 (16B chunks)
#pragma unroll
        for (int j = 0; j < 2; ++j) {
            int idx = tid + 256 * j;  // 0..511
            int c = idx >> 2, q = idx & 3;
            uint4 v = *reinterpret_cast<const uint4*>(&wt[c * IN_F + kt * 32 + q * 8]);
            *reinterpret_cast<uint4*>(&ws[c * LDK + q * 8]) = v;
        }
        __syncthreads();

        bf16x8 af[4], bfr[4];
#pragma unroll
        for (int m = 0; m < 4; ++m)
            af[m] = *reinterpret_cast<const bf16x8*>(&xs[(wr + m * 16 + l15) * LDK + kg]);
#pragma unroll
        for (int n = 0; n < 4; ++n)
            bfr[n] = *reinterpret_cast<const bf16x8*>(&ws[(wc + n * 16 + l15) * LDK + kg]);
#pragma unroll
        for (int m = 0; m < 4; ++m)
#pragma unroll
            for (int n = 0; n < 4; ++n)
                acc[m][n] = __builtin_amdgcn_mfma_f32_16x16x32_bf16(af[m], bfr[n], acc[m][n], 0, 0, 0);
    }

    // epilogue: C/D layout col=lane&15, row=(lane>>4)*4+r  -> bf16 stores
#pragma unroll
    for (int m = 0; m < 4; ++m) {
#pragma unroll
        for (int r = 0; r < 4; ++r) {
            int row = row0 + wr + m * 16 + (lane >> 4) * 4 + r;
            if (row < N_NODES) {
#pragma unroll
                for (int n = 0; n < 4; ++n) {
                    support[(size_t)row * OUT_F + wc + n * 16 + l15] = f2bf(acc[m][n][r]);
                }
            }
        }
    }
}

// ---------------------------------------------------------------------------
// CSR build: counting sort of edges by destination node. (unchanged)
// ---------------------------------------------------------------------------
__global__ __launch_bounds__(256) void zero_kernel(int* __restrict__ p, int n) {
    int i = blockIdx.x * 256 + threadIdx.x;
    if (i < n) p[i] = 0;
}

__global__ __launch_bounds__(256) void hist_kernel(const int* __restrict__ rowi,
                                                   int* __restrict__ counts) {
    int e = blockIdx.x * 256 + threadIdx.x;
    if (e < N_EDGES) atomicAdd(&counts[rowi[e]], 1);
}

__global__ __launch_bounds__(256) void scan1_kernel(int* __restrict__ data,
                                                    int* __restrict__ blocksums,
                                                    int n) {
    __shared__ int sdata[256];
    const int tid = threadIdx.x;
    const int base = blockIdx.x * 1024 + tid * 4;
    int v0 = (base + 0 < n) ? data[base + 0] : 0;
    int v1 = (base + 1 < n) ? data[base + 1] : 0;
    int v2 = (base + 2 < n) ? data[base + 2] : 0;
    int v3 = (base + 3 < n) ? data[base + 3] : 0;
    int s1 = v0 + v1, s2 = s1 + v2, s3 = s2 + v3;
    sdata[tid] = s3;
    __syncthreads();
#pragma unroll
    for (int off = 1; off < 256; off <<= 1) {
        int t = (tid >= off) ? sdata[tid - off] : 0;
        __syncthreads();
        sdata[tid] += t;
        __syncthreads();
    }
    int excl = (tid == 0) ? 0 : sdata[tid - 1];
    if (base + 0 < n) data[base + 0] = excl;
    if (base + 1 < n) data[base + 1] = excl + v0;
    if (base + 2 < n) data[base + 2] = excl + s1;
    if (base + 3 < n) data[base + 3] = excl + s2;
    if (tid == 255) blocksums[blockIdx.x] = sdata[255];
}

__global__ __launch_bounds__(128) void scan2_kernel(int* __restrict__ blocksums, int nblk) {
    __shared__ int sdata[128];
    const int tid = threadIdx.x;
    sdata[tid] = (tid < nblk) ? blocksums[tid] : 0;
    __syncthreads();
#pragma unroll
    for (int off = 1; off < 128; off <<= 1) {
        int t = (tid >= off) ? sdata[tid - off] : 0;
        __syncthreads();
        sdata[tid] += t;
        __syncthreads();
    }
    if (tid < nblk) blocksums[tid] = (tid == 0) ? 0 : sdata[tid - 1];
}

__global__ __launch_bounds__(256) void scan3_kernel(int* __restrict__ data,
                                                    const int* __restrict__ blocksums,
                                                    int n) {
    int i = blockIdx.x * 1024 + threadIdx.x * 4;
    int b = blocksums[blockIdx.x];
    if (i + 0 < n) data[i + 0] += b;
    if (i + 1 < n) data[i + 1] += b;
    if (i + 2 < n) data[i + 2] += b;
    if (i + 3 < n) data[i + 3] += b;
}

__global__ __launch_bounds__(256) void sortscat_kernel(const int* __restrict__ rowi,
                                                       const int* __restrict__ coli,
                                                       const float* __restrict__ val,
                                                       int* __restrict__ offsets,
                                                       uint2* __restrict__ pairs) {
    int e = blockIdx.x * 256 + threadIdx.x;
    if (e < N_EDGES) {
        int dst = rowi[e];
        int pos = atomicAdd(&offsets[dst], 1);
        pairs[pos] = make_uint2((unsigned)coli[e], __float_as_uint(val[e]));
    }
}

// ---------------------------------------------------------------------------
// accumulate: one wave64 per node; support is bf16 (halved gather traffic).
// 32 lanes x 4 bf16 cover 128 feats; two wave halves process alternating
// edges, combined via shfl_xor(32). out = acc + bias, plain stores.
// ---------------------------------------------------------------------------
__global__ __launch_bounds__(256) void accum_kernel(const unsigned short* __restrict__ support,
                                                    const uint2* __restrict__ pairs,
                                                    const int* __restrict__ offsets,
                                                    const float* __restrict__ bias,
                                                    float* __restrict__ out) {
    const int node = blockIdx.x * 4 + (threadIdx.x >> 6);
    const int lane = threadIdx.x & 63;
    const int half = lane >> 5;
    const int f4 = lane & 31;
    if (node >= N_NODES) return;

    const int start = (node == 0) ? 0 : offsets[node - 1];
    const int end = offsets[node];

    float4 acc = make_float4(0.f, 0.f, 0.f, 0.f);
    for (int p = start + half; p < end; p += 2) {
        uint2 pr = pairs[p];
        float v = __uint_as_float(pr.y);
        ushort4 s = *reinterpret_cast<const ushort4*>(&support[(size_t)pr.x * OUT_F + f4 * 4]);
        acc.x += bf2f(s.x) * v;
        acc.y += bf2f(s.y) * v;
        acc.z += bf2f(s.z) * v;
        acc.w += bf2f(s.w) * v;
    }
    acc.x += __shfl_xor(acc.x, 32);
    acc.y += __shfl_xor(acc.y, 32);
    acc.z += __shfl_xor(acc.z, 32);
    acc.w += __shfl_xor(acc.w, 32);

    if (half == 0) {
        float4 b = *reinterpret_cast<const float4*>(&bias[f4 * 4]);
        float4 o = make_float4(acc.x + b.x, acc.y + b.y, acc.z + b.z, acc.w + b.w);
        *reinterpret_cast<float4*>(&out[(size_t)node * OUT_F + f4 * 4]) = o;
    }
}

extern "C" void kernel_launch(void* const* d_in, const int* in_sizes, int n_in,
                              void* d_out, int out_size, void* d_ws, size_t ws_size,
                              hipStream_t stream) {
    const float* x       = (const float*)d_in[0];
    const float* weight  = (const float*)d_in[1];
    const float* bias    = (const float*)d_in[2];
    const float* adj_val = (const float*)d_in[3];
    const int*   adj_row = (const int*)d_in[4];
    const int*   adj_col = (const int*)d_in[5];
    float* out = (float*)d_out;

    // workspace layout:
    //   support_bf : 12.8M ushort (25.6 MB)
    //   wt         : 32768 ushort (64 KB)
    //   offsets    : 100000 int
    //   blocksums  : 132 int (pad to keep pairs 8B-aligned)
    //   pairs      : 1.6M uint2 (12.8 MB)
    unsigned short* support = (unsigned short*)d_ws;
    unsigned short* wt = support + (size_t)N_NODES * OUT_F;
    int* offsets = (int*)(wt + IN_F * OUT_F);
    int* blocksums = offsets + 100000;
    uint2* pairs = (uint2*)(blocksums + 132);

    const int NSCAN_BLOCKS = (N_NODES + 1023) / 1024;  // 98

    // 1) weight transpose+convert, then support = bf16 MFMA GEMM
    wtrans_kernel<<<OUT_F, 256, 0, stream>>>(weight, wt);
    gemm_mfma_kernel<<<(N_NODES + 127) / 128, 256, 0, stream>>>(x, wt, support);

    // 2) CSR build
    zero_kernel<<<(N_NODES + 255) / 256, 256, 0, stream>>>(offsets, N_NODES);
    hist_kernel<<<(N_EDGES + 255) / 256, 256, 0, stream>>>(adj_row, offsets);
    scan1_kernel<<<NSCAN_BLOCKS, 256, 0, stream>>>(offsets, blocksums, N_NODES);
    scan2_kernel<<<1, 128, 0, stream>>>(blocksums, NSCAN_BLOCKS);
    scan3_kernel<<<NSCAN_BLOCKS, 256, 0, stream>>>(offsets, blocksums, N_NODES);
    sortscat_kernel<<<(N_EDGES + 255) / 256, 256, 0, stream>>>(adj_row, adj_col, adj_val,
                                                               offsets, pairs);

    // 3) accumulate per destination node
    accum_kernel<<<(N_NODES + 3) / 4, 256, 0, stream>>>(support, pairs, offsets, bias, out);
}

// Round 4
// 184.569 us; speedup vs baseline: 15.3574x; 1.7321x over previous
//
#include <hip/hip_runtime.h>

#define N_NODES 100000
#define N_EDGES 1600000
#define IN_F 256
#define OUT_F 128
#define LDK 40  // padded k-stride (bf16 elems) for LDS tiles

// two-level counting sort params
#define NBUCK 391            // ceil(N_NODES / 256): coarse bucket = dst >> 8
#define NCHUNK 256           // edge chunks (one block each)
#define CHUNK_E (N_EDGES / NCHUNK)  // 6250
#define NSCAN (NBUCK * NCHUNK)      // 100096 count-matrix entries

typedef __attribute__((ext_vector_type(8))) short bf16x8;
typedef __attribute__((ext_vector_type(4))) float f32x4;

__device__ __forceinline__ unsigned short f2bf(float f) {
    unsigned u = __float_as_uint(f);
    unsigned r = u + 0x7fffu + ((u >> 16) & 1u);  // RNE
    return (unsigned short)(r >> 16);
}
__device__ __forceinline__ float bf2f(unsigned short u) {
    return __uint_as_float(((unsigned)u) << 16);
}

// ---------------------------------------------------------------------------
// wt[col][k] (bf16) = w[k][col]
// ---------------------------------------------------------------------------
__global__ __launch_bounds__(256) void wtrans_kernel(const float* __restrict__ w,
                                                     unsigned short* __restrict__ wt) {
    int c = blockIdx.x;
    int k = threadIdx.x;
    wt[c * IN_F + k] = f2bf(w[k * OUT_F + c]);
}

// ---------------------------------------------------------------------------
// GEMM: support_bf16[N][128] = bf16(x) @ bf16(w). (unchanged from round 3)
// ---------------------------------------------------------------------------
__global__ __launch_bounds__(256) void gemm_mfma_kernel(const float* __restrict__ x,
                                                        const unsigned short* __restrict__ wt,
                                                        unsigned short* __restrict__ support) {
    __shared__ unsigned short xs[128 * LDK];
    __shared__ unsigned short ws[128 * LDK];

    const int tid = threadIdx.x;
    const int lane = tid & 63;
    const int wv = tid >> 6;
    const int wr = (wv >> 1) * 64;
    const int wc = (wv & 1) * 64;
    const int row0 = blockIdx.x * 128;
    const int l15 = lane & 15;
    const int kg = (lane >> 4) * 8;

    f32x4 acc[4][4];
#pragma unroll
    for (int m = 0; m < 4; ++m)
#pragma unroll
        for (int n = 0; n < 4; ++n) acc[m][n] = (f32x4){0.f, 0.f, 0.f, 0.f};

    for (int kt = 0; kt < 8; ++kt) {
        __syncthreads();
#pragma unroll
        for (int i = 0; i < 4; ++i) {
            int idx = tid + 256 * i;
            int r = idx >> 3, q = idx & 7;
            int grow = row0 + r;
            if (grow > N_NODES - 1) grow = N_NODES - 1;
            float4 v = *reinterpret_cast<const float4*>(&x[(size_t)grow * IN_F + kt * 32 + q * 4]);
            ushort4 b;
            b.x = f2bf(v.x); b.y = f2bf(v.y); b.z = f2bf(v.z); b.w = f2bf(v.w);
            *reinterpret_cast<ushort4*>(&xs[r * LDK + q * 4]) = b;
        }
#pragma unroll
        for (int j = 0; j < 2; ++j) {
            int idx = tid + 256 * j;
            int c = idx >> 2, q = idx & 3;
            uint4 v = *reinterpret_cast<const uint4*>(&wt[c * IN_F + kt * 32 + q * 8]);
            *reinterpret_cast<uint4*>(&ws[c * LDK + q * 8]) = v;
        }
        __syncthreads();

        bf16x8 af[4], bfr[4];
#pragma unroll
        for (int m = 0; m < 4; ++m)
            af[m] = *reinterpret_cast<const bf16x8*>(&xs[(wr + m * 16 + l15) * LDK + kg]);
#pragma unroll
        for (int n = 0; n < 4; ++n)
            bfr[n] = *reinterpret_cast<const bf16x8*>(&ws[(wc + n * 16 + l15) * LDK + kg]);
#pragma unroll
        for (int m = 0; m < 4; ++m)
#pragma unroll
            for (int n = 0; n < 4; ++n)
                acc[m][n] = __builtin_amdgcn_mfma_f32_16x16x32_bf16(af[m], bfr[n], acc[m][n], 0, 0, 0);
    }

#pragma unroll
    for (int m = 0; m < 4; ++m) {
#pragma unroll
        for (int r = 0; r < 4; ++r) {
            int row = row0 + wr + m * 16 + (lane >> 4) * 4 + r;
            if (row < N_NODES) {
#pragma unroll
                for (int n = 0; n < 4; ++n) {
                    support[(size_t)row * OUT_F + wc + n * 16 + l15] = f2bf(acc[m][n][r]);
                }
            }
        }
    }
}

// ---------------------------------------------------------------------------
// Sort phase 1: per-chunk coarse histogram. counts[bucket][chunk] layout
// (bucket-major) so one exclusive scan yields per-(chunk,bucket) bases.
// ---------------------------------------------------------------------------
__global__ __launch_bounds__(256) void count_kernel(const int* __restrict__ rowi,
                                                    int* __restrict__ counts) {
    __shared__ int hist[NBUCK];
    const int tid = threadIdx.x, c = blockIdx.x;
    for (int i = tid; i < NBUCK; i += 256) hist[i] = 0;
    __syncthreads();
    const int e0 = c * CHUNK_E;
    for (int i = tid; i < CHUNK_E; i += 256)
        atomicAdd(&hist[rowi[e0 + i] >> 8], 1);
    __syncthreads();
    for (int i = tid; i < NBUCK; i += 256) counts[i * NCHUNK + c] = hist[i];
}

// scan1/scan2/scan3: exclusive scan of counts[NSCAN] in place.
__global__ __launch_bounds__(256) void scan1_kernel(int* __restrict__ data,
                                                    int* __restrict__ blocksums,
                                                    int n) {
    __shared__ int sdata[256];
    const int tid = threadIdx.x;
    const int base = blockIdx.x * 1024 + tid * 4;
    int v0 = (base + 0 < n) ? data[base + 0] : 0;
    int v1 = (base + 1 < n) ? data[base + 1] : 0;
    int v2 = (base + 2 < n) ? data[base + 2] : 0;
    int v3 = (base + 3 < n) ? data[base + 3] : 0;
    int s1 = v0 + v1, s2 = s1 + v2, s3 = s2 + v3;
    sdata[tid] = s3;
    __syncthreads();
#pragma unroll
    for (int off = 1; off < 256; off <<= 1) {
        int t = (tid >= off) ? sdata[tid - off] : 0;
        __syncthreads();
        sdata[tid] += t;
        __syncthreads();
    }
    int excl = (tid == 0) ? 0 : sdata[tid - 1];
    if (base + 0 < n) data[base + 0] = excl;
    if (base + 1 < n) data[base + 1] = excl + v0;
    if (base + 2 < n) data[base + 2] = excl + s1;
    if (base + 3 < n) data[base + 3] = excl + s2;
    if (tid == 255) blocksums[blockIdx.x] = sdata[255];
}

__global__ __launch_bounds__(128) void scan2_kernel(int* __restrict__ blocksums, int nblk) {
    __shared__ int sdata[128];
    const int tid = threadIdx.x;
    sdata[tid] = (tid < nblk) ? blocksums[tid] : 0;
    __syncthreads();
#pragma unroll
    for (int off = 1; off < 128; off <<= 1) {
        int t = (tid >= off) ? sdata[tid - off] : 0;
        __syncthreads();
        sdata[tid] += t;
        __syncthreads();
    }
    if (tid < nblk) blocksums[tid] = (tid == 0) ? 0 : sdata[tid - 1];
}

__global__ __launch_bounds__(256) void scan3_kernel(int* __restrict__ data,
                                                    const int* __restrict__ blocksums,
                                                    int n) {
    int i = blockIdx.x * 1024 + threadIdx.x * 4;
    int b = blocksums[blockIdx.x];
    if (i + 0 < n) data[i + 0] += b;
    if (i + 1 < n) data[i + 1] += b;
    if (i + 2 < n) data[i + 2] += b;
    if (i + 3 < n) data[i + 3] += b;
}

// ---------------------------------------------------------------------------
// Sort phase 2: coarse scatter. Each chunk-block owns exclusive contiguous
// ranges per bucket (from the scan) -> zero global atomics, write runs of
// ~16 edges come from a single block -> L2 write-combining.
// tmp entry: x = (dst_low8 << 17) | col, y = val bits.
// ---------------------------------------------------------------------------
__global__ __launch_bounds__(256) void scatter1_kernel(const int* __restrict__ rowi,
                                                       const int* __restrict__ coli,
                                                       const float* __restrict__ val,
                                                       const int* __restrict__ bases,
                                                       uint2* __restrict__ tmp) {
    __shared__ int cur[NBUCK];
    const int tid = threadIdx.x, c = blockIdx.x;
    for (int i = tid; i < NBUCK; i += 256) cur[i] = bases[i * NCHUNK + c];
    __syncthreads();
    const int e0 = c * CHUNK_E;
    for (int i = tid; i < CHUNK_E; i += 256) {
        int e = e0 + i;
        int dst = rowi[e];
        int b = dst >> 8;
        int pos = atomicAdd(&cur[b], 1);
        tmp[pos] = make_uint2(((unsigned)(dst & 255) << 17) | (unsigned)coli[e],
                              __float_as_uint(val[e]));
    }
}

// ---------------------------------------------------------------------------
// Sort phase 3: fine sort within one bucket (256 nodes, ~4K edges, 32 KB
// region -> all scatter writes land in one XCD's L2). Also writes per-node
// end offsets for accum.
// ---------------------------------------------------------------------------
__global__ __launch_bounds__(256) void fine_kernel(const uint2* __restrict__ tmp,
                                                   const int* __restrict__ bases,
                                                   uint2* __restrict__ pairs,
                                                   int* __restrict__ offsets) {
    __shared__ int hist[256];
    __shared__ int scanb[256];
    __shared__ int cur[256];
    const int tid = threadIdx.x, b = blockIdx.x;
    const int start = bases[b * NCHUNK];
    const int end = (b == NBUCK - 1) ? N_EDGES : bases[(b + 1) * NCHUNK];

    hist[tid] = 0;
    __syncthreads();
    for (int i = start + tid; i < end; i += 256)
        atomicAdd(&hist[tmp[i].x >> 17], 1);
    __syncthreads();
    int h = hist[tid];
    scanb[tid] = h;
    __syncthreads();
#pragma unroll
    for (int off = 1; off < 256; off <<= 1) {
        int t = (tid >= off) ? scanb[tid - off] : 0;
        __syncthreads();
        scanb[tid] += t;
        __syncthreads();
    }
    cur[tid] = start + scanb[tid] - h;  // exclusive scan + bucket base
    int node = (b << 8) + tid;
    if (node < N_NODES) offsets[node] = start + scanb[tid];  // inclusive = end
    __syncthreads();
    for (int i = start + tid; i < end; i += 256) {
        uint2 u = tmp[i];
        int dl = u.x >> 17;
        int pos = atomicAdd(&cur[dl], 1);
        pairs[pos] = make_uint2(u.x & 0x1FFFFu, u.y);
    }
}

// ---------------------------------------------------------------------------
// accumulate: one wave64 per node (unchanged from round 3).
// ---------------------------------------------------------------------------
__global__ __launch_bounds__(256) void accum_kernel(const unsigned short* __restrict__ support,
                                                    const uint2* __restrict__ pairs,
                                                    const int* __restrict__ offsets,
                                                    const float* __restrict__ bias,
                                                    float* __restrict__ out) {
    const int node = blockIdx.x * 4 + (threadIdx.x >> 6);
    const int lane = threadIdx.x & 63;
    const int half = lane >> 5;
    const int f4 = lane & 31;
    if (node >= N_NODES) return;

    const int start = (node == 0) ? 0 : offsets[node - 1];
    const int end = offsets[node];

    float4 acc = make_float4(0.f, 0.f, 0.f, 0.f);
    for (int p = start + half; p < end; p += 2) {
        uint2 pr = pairs[p];
        float v = __uint_as_float(pr.y);
        ushort4 s = *reinterpret_cast<const ushort4*>(&support[(size_t)pr.x * OUT_F + f4 * 4]);
        acc.x += bf2f(s.x) * v;
        acc.y += bf2f(s.y) * v;
        acc.z += bf2f(s.z) * v;
        acc.w += bf2f(s.w) * v;
    }
    acc.x += __shfl_xor(acc.x, 32);
    acc.y += __shfl_xor(acc.y, 32);
    acc.z += __shfl_xor(acc.z, 32);
    acc.w += __shfl_xor(acc.w, 32);

    if (half == 0) {
        float4 bv = *reinterpret_cast<const float4*>(&bias[f4 * 4]);
        float4 o = make_float4(acc.x + bv.x, acc.y + bv.y, acc.z + bv.z, acc.w + bv.w);
        *reinterpret_cast<float4*>(&out[(size_t)node * OUT_F + f4 * 4]) = o;
    }
}

extern "C" void kernel_launch(void* const* d_in, const int* in_sizes, int n_in,
                              void* d_out, int out_size, void* d_ws, size_t ws_size,
                              hipStream_t stream) {
    const float* x       = (const float*)d_in[0];
    const float* weight  = (const float*)d_in[1];
    const float* bias    = (const float*)d_in[2];
    const float* adj_val = (const float*)d_in[3];
    const int*   adj_row = (const int*)d_in[4];
    const int*   adj_col = (const int*)d_in[5];
    float* out = (float*)d_out;

    // workspace layout (~52.1 MB):
    //   support : 12.8M ushort (25.6 MB)
    //   wt      : 32768 ushort (64 KB)
    //   counts  : 100096 int (scanned in place -> bases)
    //   blocksums: 128 int
    //   offsets : 100000 int
    //   tmp     : 1.6M uint2 (12.8 MB)
    //   pairs   : 1.6M uint2 (12.8 MB)
    unsigned short* support = (unsigned short*)d_ws;
    unsigned short* wt = support + (size_t)N_NODES * OUT_F;
    int* counts = (int*)(wt + IN_F * OUT_F);
    int* blocksums = counts + NSCAN;
    int* offsets = blocksums + 128;
    uint2* tmp = (uint2*)(offsets + 100000);  // 100096+128+100000 ints = even -> 8B aligned
    uint2* pairs = tmp + N_EDGES;

    const int NSCAN_BLOCKS = (NSCAN + 1023) / 1024;  // 98

    // dense path
    wtrans_kernel<<<OUT_F, 256, 0, stream>>>(weight, wt);
    gemm_mfma_kernel<<<(N_NODES + 127) / 128, 256, 0, stream>>>(x, wt, support);

    // two-level counting sort of edges by destination
    count_kernel<<<NCHUNK, 256, 0, stream>>>(adj_row, counts);
    scan1_kernel<<<NSCAN_BLOCKS, 256, 0, stream>>>(counts, blocksums, NSCAN);
    scan2_kernel<<<1, 128, 0, stream>>>(blocksums, NSCAN_BLOCKS);
    scan3_kernel<<<NSCAN_BLOCKS, 256, 0, stream>>>(counts, blocksums, NSCAN);
    scatter1_kernel<<<NCHUNK, 256, 0, stream>>>(adj_row, adj_col, adj_val, counts, tmp);
    fine_kernel<<<NBUCK, 256, 0, stream>>>(tmp, counts, pairs, offsets);

    // accumulate per destination node
    accum_kernel<<<(N_NODES + 3) / 4, 256, 0, stream>>>(support, pairs, offsets, bias, out);
}

// Round 6
// 151.686 us; speedup vs baseline: 18.6866x; 1.2168x over previous
//
#include <hip/hip_runtime.h>

#define N_NODES 100000
#define N_EDGES 1600000
#define IN_F 256
#define OUT_F 128
#define LDK 40  // padded k-stride (bf16 elems) for LDS tiles

// two-level counting sort params
#define NBUCK 391            // ceil(N_NODES / 256): coarse bucket = dst >> 8
#define NCHUNK 256           // edge chunks (one block each)
#define CHUNK_E (N_EDGES / NCHUNK)  // 6250
#define NSCAN (NBUCK * NCHUNK)      // 100096 count-matrix entries

typedef __attribute__((ext_vector_type(8))) short bf16x8;
typedef __attribute__((ext_vector_type(4))) float f32x4;

__device__ __forceinline__ unsigned short f2bf(float f) {
    unsigned u = __float_as_uint(f);
    unsigned r = u + 0x7fffu + ((u >> 16) & 1u);  // RNE
    return (unsigned short)(r >> 16);
}
__device__ __forceinline__ float bf2f(unsigned short u) {
    return __uint_as_float(((unsigned)u) << 16);
}

// ---------------------------------------------------------------------------
// wt[col][k] (bf16) = w[k][col]
// ---------------------------------------------------------------------------
__global__ __launch_bounds__(256) void wtrans_kernel(const float* __restrict__ w,
                                                     unsigned short* __restrict__ wt) {
    int c = blockIdx.x;
    int k = threadIdx.x;
    wt[c * IN_F + k] = f2bf(w[k * OUT_F + c]);
}

// ---------------------------------------------------------------------------
// GEMM: support_bf16[N][128] = bf16(x) @ bf16(w). (unchanged)
// ---------------------------------------------------------------------------
__global__ __launch_bounds__(256) void gemm_mfma_kernel(const float* __restrict__ x,
                                                        const unsigned short* __restrict__ wt,
                                                        unsigned short* __restrict__ support) {
    __shared__ unsigned short xs[128 * LDK];
    __shared__ unsigned short ws[128 * LDK];

    const int tid = threadIdx.x;
    const int lane = tid & 63;
    const int wv = tid >> 6;
    const int wr = (wv >> 1) * 64;
    const int wc = (wv & 1) * 64;
    const int row0 = blockIdx.x * 128;
    const int l15 = lane & 15;
    const int kg = (lane >> 4) * 8;

    f32x4 acc[4][4];
#pragma unroll
    for (int m = 0; m < 4; ++m)
#pragma unroll
        for (int n = 0; n < 4; ++n) acc[m][n] = (f32x4){0.f, 0.f, 0.f, 0.f};

    for (int kt = 0; kt < 8; ++kt) {
        __syncthreads();
#pragma unroll
        for (int i = 0; i < 4; ++i) {
            int idx = tid + 256 * i;
            int r = idx >> 3, q = idx & 7;
            int grow = row0 + r;
            if (grow > N_NODES - 1) grow = N_NODES - 1;
            float4 v = *reinterpret_cast<const float4*>(&x[(size_t)grow * IN_F + kt * 32 + q * 4]);
            ushort4 b;
            b.x = f2bf(v.x); b.y = f2bf(v.y); b.z = f2bf(v.z); b.w = f2bf(v.w);
            *reinterpret_cast<ushort4*>(&xs[r * LDK + q * 4]) = b;
        }
#pragma unroll
        for (int j = 0; j < 2; ++j) {
            int idx = tid + 256 * j;
            int c = idx >> 2, q = idx & 3;
            uint4 v = *reinterpret_cast<const uint4*>(&wt[c * IN_F + kt * 32 + q * 8]);
            *reinterpret_cast<uint4*>(&ws[c * LDK + q * 8]) = v;
        }
        __syncthreads();

        bf16x8 af[4], bfr[4];
#pragma unroll
        for (int m = 0; m < 4; ++m)
            af[m] = *reinterpret_cast<const bf16x8*>(&xs[(wr + m * 16 + l15) * LDK + kg]);
#pragma unroll
        for (int n = 0; n < 4; ++n)
            bfr[n] = *reinterpret_cast<const bf16x8*>(&ws[(wc + n * 16 + l15) * LDK + kg]);
#pragma unroll
        for (int m = 0; m < 4; ++m)
#pragma unroll
            for (int n = 0; n < 4; ++n)
                acc[m][n] = __builtin_amdgcn_mfma_f32_16x16x32_bf16(af[m], bfr[n], acc[m][n], 0, 0, 0);
    }

#pragma unroll
    for (int m = 0; m < 4; ++m) {
#pragma unroll
        for (int r = 0; r < 4; ++r) {
            int row = row0 + wr + m * 16 + (lane >> 4) * 4 + r;
            if (row < N_NODES) {
#pragma unroll
                for (int n = 0; n < 4; ++n) {
                    support[(size_t)row * OUT_F + wc + n * 16 + l15] = f2bf(acc[m][n][r]);
                }
            }
        }
    }
}

// ---------------------------------------------------------------------------
// Sort phase 1: per-chunk coarse histogram, counts[bucket][chunk].
// ---------------------------------------------------------------------------
__global__ __launch_bounds__(256) void count_kernel(const int* __restrict__ rowi,
                                                    int* __restrict__ counts) {
    __shared__ int hist[NBUCK];
    const int tid = threadIdx.x, c = blockIdx.x;
    for (int i = tid; i < NBUCK; i += 256) hist[i] = 0;
    __syncthreads();
    const int e0 = c * CHUNK_E;
    for (int i = tid; i < CHUNK_E; i += 256)
        atomicAdd(&hist[rowi[e0 + i] >> 8], 1);
    __syncthreads();
    for (int i = tid; i < NBUCK; i += 256) counts[i * NCHUNK + c] = hist[i];
}

__global__ __launch_bounds__(256) void scan1_kernel(int* __restrict__ data,
                                                    int* __restrict__ blocksums,
                                                    int n) {
    __shared__ int sdata[256];
    const int tid = threadIdx.x;
    const int base = blockIdx.x * 1024 + tid * 4;
    int v0 = (base + 0 < n) ? data[base + 0] : 0;
    int v1 = (base + 1 < n) ? data[base + 1] : 0;
    int v2 = (base + 2 < n) ? data[base + 2] : 0;
    int v3 = (base + 3 < n) ? data[base + 3] : 0;
    int s1 = v0 + v1, s2 = s1 + v2, s3 = s2 + v3;
    sdata[tid] = s3;
    __syncthreads();
#pragma unroll
    for (int off = 1; off < 256; off <<= 1) {
        int t = (tid >= off) ? sdata[tid - off] : 0;
        __syncthreads();
        sdata[tid] += t;
        __syncthreads();
    }
    int excl = (tid == 0) ? 0 : sdata[tid - 1];
    if (base + 0 < n) data[base + 0] = excl;
    if (base + 1 < n) data[base + 1] = excl + v0;
    if (base + 2 < n) data[base + 2] = excl + s1;
    if (base + 3 < n) data[base + 3] = excl + s2;
    if (tid == 255) blocksums[blockIdx.x] = sdata[255];
}

__global__ __launch_bounds__(128) void scan2_kernel(int* __restrict__ blocksums, int nblk) {
    __shared__ int sdata[128];
    const int tid = threadIdx.x;
    sdata[tid] = (tid < nblk) ? blocksums[tid] : 0;
    __syncthreads();
#pragma unroll
    for (int off = 1; off < 128; off <<= 1) {
        int t = (tid >= off) ? sdata[tid - off] : 0;
        __syncthreads();
        sdata[tid] += t;
        __syncthreads();
    }
    if (tid < nblk) blocksums[tid] = (tid == 0) ? 0 : sdata[tid - 1];
}

__global__ __launch_bounds__(256) void scan3_kernel(int* __restrict__ data,
                                                    const int* __restrict__ blocksums,
                                                    int n) {
    int i = blockIdx.x * 1024 + threadIdx.x * 4;
    int b = blocksums[blockIdx.x];
    if (i + 0 < n) data[i + 0] += b;
    if (i + 1 < n) data[i + 1] += b;
    if (i + 2 < n) data[i + 2] += b;
    if (i + 3 < n) data[i + 3] += b;
}

// ---------------------------------------------------------------------------
// Sort phase 2: coarse scatter (no global atomics).
// ---------------------------------------------------------------------------
__global__ __launch_bounds__(256) void scatter1_kernel(const int* __restrict__ rowi,
                                                       const int* __restrict__ coli,
                                                       const float* __restrict__ val,
                                                       const int* __restrict__ bases,
                                                       uint2* __restrict__ tmp) {
    __shared__ int cur[NBUCK];
    const int tid = threadIdx.x, c = blockIdx.x;
    for (int i = tid; i < NBUCK; i += 256) cur[i] = bases[i * NCHUNK + c];
    __syncthreads();
    const int e0 = c * CHUNK_E;
    for (int i = tid; i < CHUNK_E; i += 256) {
        int e = e0 + i;
        int dst = rowi[e];
        int b = dst >> 8;
        int pos = atomicAdd(&cur[b], 1);
        tmp[pos] = make_uint2(((unsigned)(dst & 255) << 17) | (unsigned)coli[e],
                              __float_as_uint(val[e]));
    }
}

// ---------------------------------------------------------------------------
// Sort phase 3: fine sort within one bucket; writes per-node end offsets.
// ---------------------------------------------------------------------------
__global__ __launch_bounds__(256) void fine_kernel(const uint2* __restrict__ tmp,
                                                   const int* __restrict__ bases,
                                                   uint2* __restrict__ pairs,
                                                   int* __restrict__ offsets) {
    __shared__ int hist[256];
    __shared__ int scanb[256];
    __shared__ int cur[256];
    const int tid = threadIdx.x, b = blockIdx.x;
    const int start = bases[b * NCHUNK];
    const int end = (b == NBUCK - 1) ? N_EDGES : bases[(b + 1) * NCHUNK];

    hist[tid] = 0;
    __syncthreads();
    for (int i = start + tid; i < end; i += 256)
        atomicAdd(&hist[tmp[i].x >> 17], 1);
    __syncthreads();
    int h = hist[tid];
    scanb[tid] = h;
    __syncthreads();
#pragma unroll
    for (int off = 1; off < 256; off <<= 1) {
        int t = (tid >= off) ? scanb[tid - off] : 0;
        __syncthreads();
        scanb[tid] += t;
        __syncthreads();
    }
    cur[tid] = start + scanb[tid] - h;
    int node = (b << 8) + tid;
    if (node < N_NODES) offsets[node] = start + scanb[tid];
    __syncthreads();
    for (int i = start + tid; i < end; i += 256) {
        uint2 u = tmp[i];
        int dl = u.x >> 17;
        int pos = atomicAdd(&cur[dl], 1);
        pairs[pos] = make_uint2(u.x & 0x1FFFFu, u.y);
    }
}

// ---------------------------------------------------------------------------
// accumulate: one wave64 per node, 4 edge slots x 16 lanes (8 feats each).
// Unrolled x2 -> 8 independent support-row gathers in flight per wave.
// Group partials combined via shfl_xor(16/32); nontemporal out stores.
// ---------------------------------------------------------------------------
__global__ __launch_bounds__(256) void accum_kernel(const unsigned short* __restrict__ support,
                                                    const uint2* __restrict__ pairs,
                                                    const int* __restrict__ offsets,
                                                    const float* __restrict__ bias,
                                                    float* __restrict__ out) {
    const int node = blockIdx.x * 4 + (threadIdx.x >> 6);
    const int lane = threadIdx.x & 63;
    const int grp = lane >> 4;   // edge slot 0..3
    const int l16 = lane & 15;   // feature slot: feats l16*8 .. l16*8+7
    if (node >= N_NODES) return;

    const int start = (node == 0) ? 0 : offsets[node - 1];
    const int end = offsets[node];

    float acc[8];
#pragma unroll
    for (int t = 0; t < 8; ++t) acc[t] = 0.f;

    int j = start + grp;
    for (; j + 4 < end; j += 8) {
        uint2 p0 = pairs[j];
        uint2 p1 = pairs[j + 4];
        uint4 s0 = *reinterpret_cast<const uint4*>(&support[(size_t)p0.x * OUT_F + l16 * 8]);
        uint4 s1 = *reinterpret_cast<const uint4*>(&support[(size_t)p1.x * OUT_F + l16 * 8]);
        float v0 = __uint_as_float(p0.y);
        float v1 = __uint_as_float(p1.y);
        unsigned u0[4] = {s0.x, s0.y, s0.z, s0.w};
        unsigned u1[4] = {s1.x, s1.y, s1.z, s1.w};
#pragma unroll
        for (int q = 0; q < 4; ++q) {
            acc[2 * q + 0] += __uint_as_float(u0[q] << 16) * v0;
            acc[2 * q + 1] += __uint_as_float(u0[q] & 0xffff0000u) * v0;
            acc[2 * q + 0] += __uint_as_float(u1[q] << 16) * v1;
            acc[2 * q + 1] += __uint_as_float(u1[q] & 0xffff0000u) * v1;
        }
    }
    for (; j < end; j += 4) {
        uint2 p0 = pairs[j];
        uint4 s0 = *reinterpret_cast<const uint4*>(&support[(size_t)p0.x * OUT_F + l16 * 8]);
        float v0 = __uint_as_float(p0.y);
        unsigned u0[4] = {s0.x, s0.y, s0.z, s0.w};
#pragma unroll
        for (int q = 0; q < 4; ++q) {
            acc[2 * q + 0] += __uint_as_float(u0[q] << 16) * v0;
            acc[2 * q + 1] += __uint_as_float(u0[q] & 0xffff0000u) * v0;
        }
    }

    // combine the 4 edge slots
#pragma unroll
    for (int t = 0; t < 8; ++t) {
        acc[t] += __shfl_xor(acc[t], 16);
        acc[t] += __shfl_xor(acc[t], 32);
    }

    if (grp == 0) {
        float4 b0 = *reinterpret_cast<const float4*>(&bias[l16 * 8]);
        float4 b1 = *reinterpret_cast<const float4*>(&bias[l16 * 8 + 4]);
        f32x4 o0 = {acc[0] + b0.x, acc[1] + b0.y, acc[2] + b0.z, acc[3] + b0.w};
        f32x4 o1 = {acc[4] + b1.x, acc[5] + b1.y, acc[6] + b1.z, acc[7] + b1.w};
        f32x4* op = reinterpret_cast<f32x4*>(&out[(size_t)node * OUT_F + l16 * 8]);
        __builtin_nontemporal_store(o0, op);
        __builtin_nontemporal_store(o1, op + 1);
    }
}

extern "C" void kernel_launch(void* const* d_in, const int* in_sizes, int n_in,
                              void* d_out, int out_size, void* d_ws, size_t ws_size,
                              hipStream_t stream) {
    const float* x       = (const float*)d_in[0];
    const float* weight  = (const float*)d_in[1];
    const float* bias    = (const float*)d_in[2];
    const float* adj_val = (const float*)d_in[3];
    const int*   adj_row = (const int*)d_in[4];
    const int*   adj_col = (const int*)d_in[5];
    float* out = (float*)d_out;

    unsigned short* support = (unsigned short*)d_ws;
    unsigned short* wt = support + (size_t)N_NODES * OUT_F;
    int* counts = (int*)(wt + IN_F * OUT_F);
    int* blocksums = counts + NSCAN;
    int* offsets = blocksums + 128;
    uint2* tmp = (uint2*)(offsets + 100000);
    uint2* pairs = tmp + N_EDGES;

    const int NSCAN_BLOCKS = (NSCAN + 1023) / 1024;  // 98

    // dense path
    wtrans_kernel<<<OUT_F, 256, 0, stream>>>(weight, wt);
    gemm_mfma_kernel<<<(N_NODES + 127) / 128, 256, 0, stream>>>(x, wt, support);

    // two-level counting sort of edges by destination
    count_kernel<<<NCHUNK, 256, 0, stream>>>(adj_row, counts);
    scan1_kernel<<<NSCAN_BLOCKS, 256, 0, stream>>>(counts, blocksums, NSCAN);
    scan2_kernel<<<1, 128, 0, stream>>>(blocksums, NSCAN_BLOCKS);
    scan3_kernel<<<NSCAN_BLOCKS, 256, 0, stream>>>(counts, blocksums, NSCAN);
    scatter1_kernel<<<NCHUNK, 256, 0, stream>>>(adj_row, adj_col, adj_val, counts, tmp);
    fine_kernel<<<NBUCK, 256, 0, stream>>>(tmp, counts, pairs, offsets);

    // accumulate per destination node
    accum_kernel<<<(N_NODES + 3) / 4, 256, 0, stream>>>(support, pairs, offsets, bias, out);
}